// Round 1
// baseline (36884.973 us; speedup 1.0000x reference)
//
#include <hip/hip_runtime.h>
#include <stdint.h>

#define B_ 64
#define T_ 2048
#define I_ 512
#define H_ 512

typedef short bf16x8 __attribute__((ext_vector_type(8)));
typedef float f32x4 __attribute__((ext_vector_type(4)));

__device__ __forceinline__ unsigned short f2bf(float f) {
  union { float f; unsigned u; } x; x.f = f;
  unsigned r = x.u + 0x7fffu + ((x.u >> 16) & 1u);
  return (unsigned short)(r >> 16);
}
__device__ __forceinline__ float sigm(float x) { return 1.0f / (1.0f + __expf(-x)); }
__device__ __forceinline__ float tanhfast(float x) { return 1.0f - 2.0f / (__expf(2.0f * x) + 1.0f); }

// Kernel 1: zero barrier flags + convert inputs (B,T,I) f32 -> (T,B,I) bf16
__global__ void prep_kernel(const float* __restrict__ in, unsigned short* __restrict__ xbf,
                            unsigned int* __restrict__ flags) {
  int t = blockIdx.x;
  int tid = threadIdx.x;
  if (t == 0) {
    for (int i = tid; i < 4096; i += 256) flags[i] = 0u;  // 256 flags x 16 dwords padding
  }
  const int slab = B_ * I_;  // 32768
  for (int idx = tid * 4; idx < slab; idx += 256 * 4) {
    int b = idx >> 9;
    int i = idx & 511;
    const float4 v = *reinterpret_cast<const float4*>(in + ((size_t)b * T_ + t) * I_ + i);
    ushort4 o;
    o.x = f2bf(v.x); o.y = f2bf(v.y); o.z = f2bf(v.z); o.w = f2bf(v.w);
    *reinterpret_cast<ushort4*>(xbf + (size_t)t * slab + idx) = o;
  }
}

// Persistent LSTM kernel: 256 WGs = 4 batch-groups (16 rows) x 64 col-slices (8 h-cols).
// Each WG: 1 wave (64 threads), holds its 512x32-gate-col slice of [Wi;Wh] in LDS
// (bf16, pre-packed in MFMA B-fragment order), c-state in registers.
// Per step: acc = bias; x-GEMM (16 MFMA ksteps, no dependency); barrier-wait on group
// flags; h-GEMM (16 ksteps); activations via LDS remap; write o_t, h_{t+1}; release flag.
__global__ __launch_bounds__(64, 1) void lstm_kernel(
    const float* __restrict__ Wi, const float* __restrict__ bi,
    const float* __restrict__ Wh, const float* __restrict__ bh,
    const unsigned short* __restrict__ xbf,
    unsigned short* __restrict__ hbuf,
    unsigned int* flags,
    float* __restrict__ out, float* __restrict__ hT)
{
  const int wg = blockIdx.x;
  const int bg = wg >> 6;    // batch group 0..3
  const int gc = wg & 63;    // col-slice 0..63
  const int lane = threadIdx.x;

  extern __shared__ char lds[];
  short* Wp = (short*)lds;               // 32 ksteps x 2 tiles x 64 lanes x 8 = 64KB
  float* gates = (float*)(lds + 65536);  // 16 x 32 f32 = 2KB

  // ---- pack weight slice into LDS as B fragments; combined K: [0,512)=Wi, [512,1024)=Wh
  {
    const int n = lane & 31;                                   // gate-col index 0..31
    const int col = ((n >> 3) << 9) + (gc << 3) + (n & 7);     // q*512 + gc*8 + j
    for (int kf = (lane >> 5); kf < 1024; kf += 2) {
      float v = (kf < 512) ? Wi[(size_t)kf * 2048 + col]
                           : Wh[(size_t)(kf - 512) * 2048 + col];
      int kk = kf >> 5;
      int lp = (((kf & 31) >> 3) << 4) + (n & 15);             // B-frag lane
      int tl = n >> 4;                                          // N-tile
      Wp[((((kk << 1) + tl) << 6) + lp) * 8 + (kf & 7)] = (short)f2bf(v);
    }
  }
  // bias (bi + bh folded into accumulator init), per acc tile column
  const int n0 = lane & 15;
  const int col0 = ((n0 >> 3) << 9) + (gc << 3) + (n0 & 7);
  const int n1 = n0 + 16;
  const int col1 = ((n1 >> 3) << 9) + (gc << 3) + (n1 & 7);
  const float rb0 = bi[col0] + bh[col0];
  const float rb1 = bi[col1] + bh[col1];
  __syncthreads();

  const int bbase = bg << 4;
  const size_t arow = ((size_t)(bbase + (lane & 15))) * 512 + ((lane >> 4) << 3);
  const short* wl = Wp + (lane << 3);
  const int jc = gc << 3;
  const int b_l = lane >> 2;           // local batch row for activation (0..15)
  const int j0 = (lane & 3) << 1;      // h-col pair within slice
  const int brow = bbase + b_l;

  float c0 = 0.f, c1 = 0.f;
  unsigned int* myflag = flags + wg * 16;
  unsigned int* pollflag = flags + (((bg << 6) + lane)) * 16;

  for (int t = 0; t < T_; ++t) {
    f32x4 acc0 = {rb0, rb0, rb0, rb0};
    f32x4 acc1 = {rb1, rb1, rb1, rb1};
    // x contribution first: no dependence on h -> overlaps barrier latency
    const unsigned short* xrow = xbf + (size_t)t * (B_ * I_) + arow;
#pragma unroll
    for (int kk = 0; kk < 16; ++kk) {
      bf16x8 a  = *reinterpret_cast<const bf16x8*>(xrow + (kk << 5));
      bf16x8 w0 = *reinterpret_cast<const bf16x8*>(wl + (kk << 10));
      bf16x8 w1 = *reinterpret_cast<const bf16x8*>(wl + (kk << 10) + 512);
      acc0 = __builtin_amdgcn_mfma_f32_16x16x32_bf16(a, w0, acc0, 0, 0, 0);
      acc1 = __builtin_amdgcn_mfma_f32_16x16x32_bf16(a, w1, acc1, 0, 0, 0);
    }
    if (t > 0) {
      // wait for whole batch-group to have published h_t
      const unsigned int want = (unsigned int)t;
      while (__hip_atomic_load(pollflag, __ATOMIC_RELAXED, __HIP_MEMORY_SCOPE_AGENT) < want)
        __builtin_amdgcn_s_sleep(1);
      __threadfence();  // acquire: invalidate stale h lines (cross-XCD)
      const unsigned short* hrow = hbuf + (size_t)(t & 1) * (B_ * H_) + arow;
#pragma unroll
      for (int kk = 0; kk < 16; ++kk) {
        bf16x8 a  = *reinterpret_cast<const bf16x8*>(hrow + (kk << 5));
        bf16x8 w0 = *reinterpret_cast<const bf16x8*>(wl + ((kk + 16) << 10));
        bf16x8 w1 = *reinterpret_cast<const bf16x8*>(wl + ((kk + 16) << 10) + 512);
        acc0 = __builtin_amdgcn_mfma_f32_16x16x32_bf16(a, w0, acc0, 0, 0, 0);
        acc1 = __builtin_amdgcn_mfma_f32_16x16x32_bf16(a, w1, acc1, 0, 0, 0);
      }
    }
    // C/D layout: col = lane&15, row = (lane>>4)*4 + r  -> remap through LDS
    {
      const int cc = lane & 15;
      const int rb = (lane >> 4) << 2;
#pragma unroll
      for (int r = 0; r < 4; ++r) {
        gates[(rb + r) * 32 + cc] = acc0[r];
        gates[(rb + r) * 32 + 16 + cc] = acc1[r];
      }
    }
    __syncthreads();
    const float* grow = gates + b_l * 32;
    float gi0 = grow[j0],      gi1 = grow[j0 + 1];
    float gf0 = grow[8 + j0],  gf1 = grow[9 + j0];
    float gg0 = grow[16 + j0], gg1 = grow[17 + j0];
    float go0 = grow[24 + j0], go1 = grow[25 + j0];
    __syncthreads();  // protect gates LDS against next-iter overwrite
    float o0 = sigm(go0), o1 = sigm(go1);
    c0 = sigm(gf0) * c0 + sigm(gi0) * tanhfast(gg0);
    c1 = sigm(gf1) * c1 + sigm(gi1) * tanhfast(gg1);
    float h0 = o0 * tanhfast(c0);
    float h1 = o1 * tanhfast(c1);
    // reference output per step is o_t
    float* orow = out + ((size_t)brow * T_ + t) * H_ + jc + j0;
    orow[0] = o0; orow[1] = o1;
    unsigned short* hw = hbuf + (size_t)((t + 1) & 1) * (B_ * H_) + (size_t)brow * H_ + jc + j0;
    hw[0] = f2bf(h0); hw[1] = f2bf(h1);
    if (t == T_ - 1) {
      float* hTo = hT + (size_t)brow * H_ + jc + j0;
      hTo[0] = h0; hTo[1] = h1;
    }
    __threadfence();  // release: make h_{t+1}/out visible agent-wide
    if (lane == 0 && t < T_ - 1)
      __hip_atomic_store(myflag, (unsigned int)(t + 1), __ATOMIC_RELEASE, __HIP_MEMORY_SCOPE_AGENT);
  }
}

extern "C" void kernel_launch(void* const* d_in, const int* in_sizes, int n_in,
                              void* d_out, int out_size, void* d_ws, size_t ws_size,
                              hipStream_t stream) {
  const float* inputs = (const float*)d_in[0];
  const float* Wi = (const float*)d_in[1];
  const float* bi = (const float*)d_in[2];
  const float* Wh = (const float*)d_in[3];
  const float* bh = (const float*)d_in[4];
  float* out = (float*)d_out;
  float* hT = out + (size_t)B_ * T_ * H_;

  // workspace layout: [flags 16KB][hbuf 2x64KB][xbf 128MB]
  unsigned int* flags = (unsigned int*)d_ws;
  unsigned short* hbuf = (unsigned short*)((char*)d_ws + 16384);
  unsigned short* xbf = (unsigned short*)((char*)d_ws + 16384 + 2 * B_ * H_ * 2);

  (void)hipFuncSetAttribute((const void*)lstm_kernel,
                            hipFuncAttributeMaxDynamicSharedMemorySize, 67584);

  prep_kernel<<<dim3(T_), dim3(256), 0, stream>>>(inputs, xbf, flags);
  lstm_kernel<<<dim3(256), dim3(64), 67584, stream>>>(Wi, bi, Wh, bh, xbf, hbuf, flags, out, hT);
}

// Round 2
// 15220.079 us; speedup vs baseline: 2.4234x; 2.4234x over previous
//
#include <hip/hip_runtime.h>
#include <stdint.h>

#define B_ 64
#define T_ 2048
#define I_ 512
#define H_ 512

typedef short bf16x8 __attribute__((ext_vector_type(8)));
typedef float f32x4 __attribute__((ext_vector_type(4)));

__device__ __forceinline__ unsigned short f2bf(float f) {
  union { float f; unsigned u; } x; x.f = f;
  unsigned r = x.u + 0x7fffu + ((x.u >> 16) & 1u);
  return (unsigned short)(r >> 16);
}
__device__ __forceinline__ float sigm(float x) { return 1.0f / (1.0f + __expf(-x)); }
__device__ __forceinline__ float tanhfast(float x) { return 1.0f - 2.0f / (__expf(2.0f * x) + 1.0f); }

// Kernel 1: zero barrier flags + convert inputs (B,T,I) f32 -> (T,B,I) bf16
__global__ void prep_kernel(const float* __restrict__ in, unsigned short* __restrict__ xbf,
                            unsigned int* __restrict__ flags) {
  int t = blockIdx.x;
  int tid = threadIdx.x;
  if (t == 0) {
    for (int i = tid; i < 1024; i += 256) flags[i] = 0u;
  }
  const int slab = B_ * I_;  // 32768
  for (int idx = tid * 4; idx < slab; idx += 256 * 4) {
    int b = idx >> 9;
    int i = idx & 511;
    const float4 v = *reinterpret_cast<const float4*>(in + ((size_t)b * T_ + t) * I_ + i);
    ushort4 o;
    o.x = f2bf(v.x); o.y = f2bf(v.y); o.z = f2bf(v.z); o.w = f2bf(v.w);
    *reinterpret_cast<ushort4*>(xbf + (size_t)t * slab + idx) = o;
  }
}

// Persistent LSTM kernel: 256 WGs = 4 batch-groups (16 rows) x 64 col-slices (8 h-cols).
// Weights LDS-resident in MFMA B-fragment order; c-state in registers.
// Cross-WG h exchange: agent-scope relaxed atomics only (memory-side coherent on
// gfx950) -> NO threadfence, NO buffer_wbl2/buffer_inv per step. Ordering of
// h-stores before the flag store is a bare s_waitcnt vmcnt(0).
__global__ __launch_bounds__(64, 1) void lstm_kernel(
    const float* __restrict__ Wi, const float* __restrict__ bi,
    const float* __restrict__ Wh, const float* __restrict__ bh,
    const unsigned short* __restrict__ xbf,
    unsigned short* __restrict__ hbuf,
    unsigned int* flags,
    float* __restrict__ out, float* __restrict__ hT)
{
  const int wg = blockIdx.x;
  const int bg = wg >> 6;    // batch group 0..3
  const int gc = wg & 63;    // col-slice 0..63
  const int lane = threadIdx.x;

  extern __shared__ char lds[];
  short* Wp = (short*)lds;               // 32 ksteps x 2 tiles x 64 lanes x 8 = 64KB
  float* gates = (float*)(lds + 65536);  // 16 x 32 f32 = 2KB

  // ---- pack weight slice into LDS as B fragments; combined K: [0,512)=Wi, [512,1024)=Wh
  {
    const int n = lane & 31;                                   // gate-col index 0..31
    const int col = ((n >> 3) << 9) + (gc << 3) + (n & 7);     // q*512 + gc*8 + j
    for (int kf = (lane >> 5); kf < 1024; kf += 2) {
      float v = (kf < 512) ? Wi[(size_t)kf * 2048 + col]
                           : Wh[(size_t)(kf - 512) * 2048 + col];
      int kk = kf >> 5;
      int lp = (((kf & 31) >> 3) << 4) + (n & 15);             // B-frag lane
      int tl = n >> 4;                                          // N-tile
      Wp[((((kk << 1) + tl) << 6) + lp) * 8 + (kf & 7)] = (short)f2bf(v);
    }
  }
  const int n0 = lane & 15;
  const int col0 = ((n0 >> 3) << 9) + (gc << 3) + (n0 & 7);
  const int n1 = n0 + 16;
  const int col1 = ((n1 >> 3) << 9) + (gc << 3) + (n1 & 7);
  const float rb0 = bi[col0] + bh[col0];
  const float rb1 = bi[col1] + bh[col1];
  __syncthreads();

  const int bbase = bg << 4;
  const size_t arow = ((size_t)(bbase + (lane & 15))) * 512 + ((lane >> 4) << 3);
  const short* wl = Wp + (lane << 3);
  const int jc = gc << 3;
  const int b_l = lane >> 2;           // local batch row for activation (0..15)
  const int j0 = (lane & 3) << 1;      // h-col pair within slice
  const int brow = bbase + b_l;

  float c0 = 0.f, c1 = 0.f;
  unsigned int* myflag = flags + wg;
  unsigned int* pollflag = flags + (bg << 6) + lane;

  for (int t = 0; t < T_; ++t) {
    f32x4 acc0 = {rb0, rb0, rb0, rb0};
    f32x4 acc1 = {rb1, rb1, rb1, rb1};
    // x contribution first: no dependence on h -> off the sync critical path
    const unsigned short* xrow = xbf + (size_t)t * (B_ * I_) + arow;
#pragma unroll
    for (int kk = 0; kk < 16; ++kk) {
      bf16x8 a  = *reinterpret_cast<const bf16x8*>(xrow + (kk << 5));
      bf16x8 w0 = *reinterpret_cast<const bf16x8*>(wl + (kk << 10));
      bf16x8 w1 = *reinterpret_cast<const bf16x8*>(wl + (kk << 10) + 512);
      acc0 = __builtin_amdgcn_mfma_f32_16x16x32_bf16(a, w0, acc0, 0, 0, 0);
      acc1 = __builtin_amdgcn_mfma_f32_16x16x32_bf16(a, w1, acc1, 0, 0, 0);
    }
    if (t > 0) {
      const unsigned int want = (unsigned int)t;
      while (__hip_atomic_load(pollflag, __ATOMIC_RELAXED, __HIP_MEMORY_SCOPE_AGENT) < want) {}
      asm volatile("" ::: "memory");  // pin h-loads after the poll exit
      const unsigned long long* h64 = reinterpret_cast<const unsigned long long*>(
          hbuf + (size_t)(t & 1) * (B_ * H_) + arow);
#pragma unroll
      for (int kk = 0; kk < 16; ++kk) {
        unsigned long long u0 = __hip_atomic_load(h64 + (kk << 3),     __ATOMIC_RELAXED, __HIP_MEMORY_SCOPE_AGENT);
        unsigned long long u1 = __hip_atomic_load(h64 + (kk << 3) + 1, __ATOMIC_RELAXED, __HIP_MEMORY_SCOPE_AGENT);
        union { unsigned long long q[2]; bf16x8 v; } a_;
        a_.q[0] = u0; a_.q[1] = u1;
        bf16x8 w0 = *reinterpret_cast<const bf16x8*>(wl + ((kk + 16) << 10));
        bf16x8 w1 = *reinterpret_cast<const bf16x8*>(wl + ((kk + 16) << 10) + 512);
        acc0 = __builtin_amdgcn_mfma_f32_16x16x32_bf16(a_.v, w0, acc0, 0, 0, 0);
        acc1 = __builtin_amdgcn_mfma_f32_16x16x32_bf16(a_.v, w1, acc1, 0, 0, 0);
      }
    }
    // C/D layout: col = lane&15, row = (lane>>4)*4 + r  -> remap through LDS
    {
      const int cc = lane & 15;
      const int rb = (lane >> 4) << 2;
#pragma unroll
      for (int r = 0; r < 4; ++r) {
        gates[(rb + r) * 32 + cc] = acc0[r];
        gates[(rb + r) * 32 + 16 + cc] = acc1[r];
      }
    }
    __syncthreads();
    const float* grow = gates + b_l * 32;
    float gi0 = grow[j0],      gi1 = grow[j0 + 1];
    float gf0 = grow[8 + j0],  gf1 = grow[9 + j0];
    float gg0 = grow[16 + j0], gg1 = grow[17 + j0];
    float go0 = grow[24 + j0], go1 = grow[25 + j0];
    __syncthreads();  // protect gates LDS against next-iter overwrite
    float o0 = sigm(go0), o1 = sigm(go1);
    c0 = sigm(gf0) * c0 + sigm(gi0) * tanhfast(gg0);
    c1 = sigm(gf1) * c1 + sigm(gi1) * tanhfast(gg1);
    float h0 = o0 * tanhfast(c0);
    float h1 = o1 * tanhfast(c1);
    // reference output per step is o_t
    float* orow = out + ((size_t)brow * T_ + t) * H_ + jc + j0;
    orow[0] = o0; orow[1] = o1;
    // h published through memory-side coherent atomic (packed 2 x bf16)
    unsigned int hpack = (unsigned int)f2bf(h0) | ((unsigned int)f2bf(h1) << 16);
    unsigned int* hw = (unsigned int*)(hbuf + (size_t)((t + 1) & 1) * (B_ * H_) + (size_t)brow * H_ + jc + j0);
    __hip_atomic_store(hw, hpack, __ATOMIC_RELAXED, __HIP_MEMORY_SCOPE_AGENT);
    if (t == T_ - 1) {
      float* hTo = hT + (size_t)brow * H_ + jc + j0;
      hTo[0] = h0; hTo[1] = h1;
    }
    // order h-stores (already at coherence point when acked) before flag store
    asm volatile("s_waitcnt vmcnt(0)" ::: "memory");
    if (lane == 0 && t < T_ - 1)
      __hip_atomic_store(myflag, (unsigned int)(t + 1), __ATOMIC_RELAXED, __HIP_MEMORY_SCOPE_AGENT);
  }
}

extern "C" void kernel_launch(void* const* d_in, const int* in_sizes, int n_in,
                              void* d_out, int out_size, void* d_ws, size_t ws_size,
                              hipStream_t stream) {
  const float* inputs = (const float*)d_in[0];
  const float* Wi = (const float*)d_in[1];
  const float* bi = (const float*)d_in[2];
  const float* Wh = (const float*)d_in[3];
  const float* bh = (const float*)d_in[4];
  float* out = (float*)d_out;
  float* hT = out + (size_t)B_ * T_ * H_;

  // workspace layout: [flags 16KB][hbuf 2x64KB][xbf 128MB]
  unsigned int* flags = (unsigned int*)d_ws;
  unsigned short* hbuf = (unsigned short*)((char*)d_ws + 16384);
  unsigned short* xbf = (unsigned short*)((char*)d_ws + 16384 + 2 * B_ * H_ * 2);

  (void)hipFuncSetAttribute((const void*)lstm_kernel,
                            hipFuncAttributeMaxDynamicSharedMemorySize, 67584);

  prep_kernel<<<dim3(T_), dim3(256), 0, stream>>>(inputs, xbf, flags);
  lstm_kernel<<<dim3(256), dim3(64), 67584, stream>>>(Wi, bi, Wh, bh, xbf, hbuf, flags, out, hT);
}

// Round 3
// 6797.231 us; speedup vs baseline: 5.4265x; 2.2392x over previous
//
#include <hip/hip_runtime.h>
#include <stdint.h>

#define B_ 64
#define T_ 2048
#define I_ 512
#define H_ 512

typedef short bf16x8 __attribute__((ext_vector_type(8)));
typedef float f32x4 __attribute__((ext_vector_type(4)));

__device__ __forceinline__ unsigned short f2bf(float f) {
  union { float f; unsigned u; } x; x.f = f;
  unsigned r = x.u + 0x7fffu + ((x.u >> 16) & 1u);
  return (unsigned short)(r >> 16);
}
__device__ __forceinline__ float sigm(float x) { return 1.0f / (1.0f + __expf(-x)); }
__device__ __forceinline__ float tanhfast(float x) { return 1.0f - 2.0f / (__expf(2.0f * x) + 1.0f); }

// Kernel 1: zero barrier flags + convert inputs (B,T,I) f32 -> (T,B,I) bf16
__global__ void prep_kernel(const float* __restrict__ in, unsigned short* __restrict__ xbf,
                            unsigned int* __restrict__ flags) {
  int t = blockIdx.x;
  int tid = threadIdx.x;
  if (t == 0) {
    for (int i = tid; i < 1024; i += 256) flags[i] = 0u;
  }
  const int slab = B_ * I_;  // 32768
  for (int idx = tid * 4; idx < slab; idx += 256 * 4) {
    int b = idx >> 9;
    int i = idx & 511;
    const float4 v = *reinterpret_cast<const float4*>(in + ((size_t)b * T_ + t) * I_ + i);
    ushort4 o;
    o.x = f2bf(v.x); o.y = f2bf(v.y); o.z = f2bf(v.z); o.w = f2bf(v.w);
    *reinterpret_cast<ushort4*>(xbf + (size_t)t * slab + idx) = o;
  }
}

// Persistent LSTM kernel: 256 WGs = 4 batch-groups (16 rows) x 64 col-slices (8 h-cols).
// Weights LDS-resident in MFMA B-fragment order; c-state in registers.
// Cross-WG h exchange via agent-scope relaxed atomics (memory-side coherent).
// KEY (R3): all global loads of a phase are batched into registers BEFORE the
// MFMA loop (sched_barrier-pinned) so each phase costs ~1 latency, not 16x.
__global__ __launch_bounds__(64, 1) void lstm_kernel(
    const float* __restrict__ Wi, const float* __restrict__ bi,
    const float* __restrict__ Wh, const float* __restrict__ bh,
    const unsigned short* __restrict__ xbf,
    unsigned short* __restrict__ hbuf,
    unsigned int* flags,
    float* __restrict__ out, float* __restrict__ hT)
{
  const int wg = blockIdx.x;
  const int bg = wg >> 6;    // batch group 0..3
  const int gc = wg & 63;    // col-slice 0..63
  const int lane = threadIdx.x;

  extern __shared__ char lds[];
  short* Wp = (short*)lds;               // 32 ksteps x 2 tiles x 64 lanes x 8 = 64KB
  float* gates = (float*)(lds + 65536);  // 16 x 32 f32 = 2KB

  // ---- pack weight slice into LDS as B fragments; combined K: [0,512)=Wi, [512,1024)=Wh
  {
    const int n = lane & 31;                                   // gate-col index 0..31
    const int col = ((n >> 3) << 9) + (gc << 3) + (n & 7);     // q*512 + gc*8 + j
    for (int kf = (lane >> 5); kf < 1024; kf += 2) {
      float v = (kf < 512) ? Wi[(size_t)kf * 2048 + col]
                           : Wh[(size_t)(kf - 512) * 2048 + col];
      int kk = kf >> 5;
      int lp = (((kf & 31) >> 3) << 4) + (n & 15);             // B-frag lane
      int tl = n >> 4;                                          // N-tile
      Wp[((((kk << 1) + tl) << 6) + lp) * 8 + (kf & 7)] = (short)f2bf(v);
    }
  }
  const int n0 = lane & 15;
  const int col0 = ((n0 >> 3) << 9) + (gc << 3) + (n0 & 7);
  const int n1 = n0 + 16;
  const int col1 = ((n1 >> 3) << 9) + (gc << 3) + (n1 & 7);
  const float rb0 = bi[col0] + bh[col0];
  const float rb1 = bi[col1] + bh[col1];
  __syncthreads();

  const int bbase = bg << 4;
  const size_t arow = ((size_t)(bbase + (lane & 15))) * 512 + ((lane >> 4) << 3);
  const short* wl = Wp + (lane << 3);
  const int jc = gc << 3;
  const int b_l = lane >> 2;           // local batch row for activation (0..15)
  const int j0 = (lane & 3) << 1;      // h-col pair within slice
  const int brow = bbase + b_l;

  float c0 = 0.f, c1 = 0.f;
  unsigned int* myflag = flags + wg;
  unsigned int* pollflag = flags + (bg << 6) + lane;

  for (int t = 0; t < T_; ++t) {
    f32x4 acc0 = {rb0, rb0, rb0, rb0};
    f32x4 acc1 = {rb1, rb1, rb1, rb1};

    // ---- phase X: batch-issue all 16 x fragments, then MFMA
    const unsigned short* xrow = xbf + (size_t)t * (B_ * I_) + arow;
    bf16x8 xa[16];
#pragma unroll
    for (int kk = 0; kk < 16; ++kk)
      xa[kk] = *reinterpret_cast<const bf16x8*>(xrow + (kk << 5));
    __builtin_amdgcn_sched_barrier(0);
#pragma unroll
    for (int kk = 0; kk < 16; ++kk) {
      bf16x8 w0 = *reinterpret_cast<const bf16x8*>(wl + (kk << 10));
      bf16x8 w1 = *reinterpret_cast<const bf16x8*>(wl + (kk << 10) + 512);
      acc0 = __builtin_amdgcn_mfma_f32_16x16x32_bf16(xa[kk], w0, acc0, 0, 0, 0);
      acc1 = __builtin_amdgcn_mfma_f32_16x16x32_bf16(xa[kk], w1, acc1, 0, 0, 0);
    }

    if (t > 0) {
      // ---- wait for whole batch-group to have published h_t
      const unsigned int want = (unsigned int)t;
      while (__hip_atomic_load(pollflag, __ATOMIC_RELAXED, __HIP_MEMORY_SCOPE_AGENT) < want) {}
      asm volatile("" ::: "memory");  // pin h-loads after the poll exit

      // ---- phase H: batch-issue all 32 h atomic loads, then MFMA
      const unsigned long long* h64 = reinterpret_cast<const unsigned long long*>(
          hbuf + (size_t)(t & 1) * (B_ * H_) + arow);
      bf16x8 ha[16];
#pragma unroll
      for (int kk = 0; kk < 16; ++kk) {
        unsigned long long u0 = __hip_atomic_load(h64 + (kk << 3),     __ATOMIC_RELAXED, __HIP_MEMORY_SCOPE_AGENT);
        unsigned long long u1 = __hip_atomic_load(h64 + (kk << 3) + 1, __ATOMIC_RELAXED, __HIP_MEMORY_SCOPE_AGENT);
        union { unsigned long long q[2]; bf16x8 v; } a_;
        a_.q[0] = u0; a_.q[1] = u1;
        ha[kk] = a_.v;
      }
      __builtin_amdgcn_sched_barrier(0);
#pragma unroll
      for (int kk = 0; kk < 16; ++kk) {
        bf16x8 w0 = *reinterpret_cast<const bf16x8*>(wl + ((kk + 16) << 10));
        bf16x8 w1 = *reinterpret_cast<const bf16x8*>(wl + ((kk + 16) << 10) + 512);
        acc0 = __builtin_amdgcn_mfma_f32_16x16x32_bf16(ha[kk], w0, acc0, 0, 0, 0);
        acc1 = __builtin_amdgcn_mfma_f32_16x16x32_bf16(ha[kk], w1, acc1, 0, 0, 0);
      }
    }

    // C/D layout: col = lane&15, row = (lane>>4)*4 + r  -> remap through LDS
    {
      const int cc = lane & 15;
      const int rb = (lane >> 4) << 2;
#pragma unroll
      for (int r = 0; r < 4; ++r) {
        gates[(rb + r) * 32 + cc] = acc0[r];
        gates[(rb + r) * 32 + 16 + cc] = acc1[r];
      }
    }
    __syncthreads();
    const float* grow = gates + b_l * 32;
    float gi0 = grow[j0],      gi1 = grow[j0 + 1];
    float gf0 = grow[8 + j0],  gf1 = grow[9 + j0];
    float gg0 = grow[16 + j0], gg1 = grow[17 + j0];
    float go0 = grow[24 + j0], go1 = grow[25 + j0];
    __syncthreads();  // protect gates LDS against next-iter overwrite
    float o0 = sigm(go0), o1 = sigm(go1);
    c0 = sigm(gf0) * c0 + sigm(gi0) * tanhfast(gg0);
    c1 = sigm(gf1) * c1 + sigm(gi1) * tanhfast(gg1);
    float h0 = o0 * tanhfast(c0);
    float h1 = o1 * tanhfast(c1);

    // ---- publish h first (critical path), outputs after the flag
    unsigned int hpack = (unsigned int)f2bf(h0) | ((unsigned int)f2bf(h1) << 16);
    unsigned int* hw = (unsigned int*)(hbuf + (size_t)((t + 1) & 1) * (B_ * H_) + (size_t)brow * H_ + jc + j0);
    __hip_atomic_store(hw, hpack, __ATOMIC_RELAXED, __HIP_MEMORY_SCOPE_AGENT);
    // order h-store (acked at coherence point) before flag store
    asm volatile("s_waitcnt vmcnt(0)" ::: "memory");
    if (lane == 0 && t < T_ - 1)
      __hip_atomic_store(myflag, (unsigned int)(t + 1), __ATOMIC_RELAXED, __HIP_MEMORY_SCOPE_AGENT);

    // reference output per step is o_t (off the sync critical path)
    float* orow = out + ((size_t)brow * T_ + t) * H_ + jc + j0;
    orow[0] = o0; orow[1] = o1;
    if (t == T_ - 1) {
      float* hTo = hT + (size_t)brow * H_ + jc + j0;
      hTo[0] = h0; hTo[1] = h1;
    }
  }
}

extern "C" void kernel_launch(void* const* d_in, const int* in_sizes, int n_in,
                              void* d_out, int out_size, void* d_ws, size_t ws_size,
                              hipStream_t stream) {
  const float* inputs = (const float*)d_in[0];
  const float* Wi = (const float*)d_in[1];
  const float* bi = (const float*)d_in[2];
  const float* Wh = (const float*)d_in[3];
  const float* bh = (const float*)d_in[4];
  float* out = (float*)d_out;
  float* hT = out + (size_t)B_ * T_ * H_;

  // workspace layout: [flags 16KB][hbuf 2x64KB][xbf 128MB]
  unsigned int* flags = (unsigned int*)d_ws;
  unsigned short* hbuf = (unsigned short*)((char*)d_ws + 16384);
  unsigned short* xbf = (unsigned short*)((char*)d_ws + 16384 + 2 * B_ * H_ * 2);

  (void)hipFuncSetAttribute((const void*)lstm_kernel,
                            hipFuncAttributeMaxDynamicSharedMemorySize, 67584);

  prep_kernel<<<dim3(T_), dim3(256), 0, stream>>>(inputs, xbf, flags);
  lstm_kernel<<<dim3(256), dim3(64), 67584, stream>>>(Wi, bi, Wh, bh, xbf, hbuf, flags, out, hT);
}